// Round 7
// baseline (595.815 us; speedup 1.0000x reference)
//
#include <hip/hip_runtime.h>
#include <math.h>

// ws layout (float offsets)
#define SB_OFF   0          // tagged strips [2][8][32][2048] = 1048576 floats
#define E_OFF    1048576    // e    [128][2048]      = 262144 floats
#define YP_OFF   1310720    // ypart[8][64][128][16] = 1048576 floats
// total 2359296 floats = 9.44 MB
// strip record (2048 floats/tile), all entries are (payload,tag) f2 pairs:
//   HT[4][32]@0  HB[4][32]@256  VL[64][4]@512  VR[64][4]@1024
//   CTL[4][4]@1536  CTR@1568  CBL@1600  CBR@1632   (offsets in floats)

__device__ __forceinline__ float fast_tanh(float x) {
  x = fminf(fmaxf(x, -15.f), 15.f);
  float ex = __expf(2.f * x);
  return __fdividef(ex - 1.f, ex + 1.f);
}

// Cross-XCD coherent data path: relaxed AGENT-scope atomics serviced at the
// coherent point (L2-bypass). 8B single-copy atomicity carries (payload,tag).
__device__ __forceinline__ float2 aload_f2(const float* p) {
  unsigned long long v = __hip_atomic_load((const unsigned long long*)p,
                                           __ATOMIC_RELAXED, __HIP_MEMORY_SCOPE_AGENT);
  float2 r;
  r.x = __uint_as_float((unsigned)v);
  r.y = __uint_as_float((unsigned)(v >> 32));
  return r;
}
__device__ __forceinline__ void astore_f2(float* p, float a, float b) {
  unsigned long long v =
      ((unsigned long long)__float_as_uint(b) << 32) | (unsigned long long)__float_as_uint(a);
  __hip_atomic_store((unsigned long long*)p, v, __ATOMIC_RELAXED, __HIP_MEMORY_SCOPE_AGENT);
}

// ---------------- K0: embed e = (X@W^T)*mask_coarse (no flags needed anymore)
__global__ __launch_bounds__(256) void prep_kernel(
    const float* __restrict__ X, const float* __restrict__ W_embed,
    const float* __restrict__ mask_coarse, float* __restrict__ ws)
{
  const int tid = threadIdx.x, bid = blockIdx.x;  // grid = 256
  float* eb = ws + E_OFF;
  const int o  = bid * 8 + (tid >> 5);     // 2048 output rows
  const int t0 = (tid & 31) * 4;           // 4 t's per thread
  const float4* Wf4 = (const float4*)W_embed + (size_t)o * 128;
  const float4* Xf4 = (const float4*)X;
  float acc[4] = {0.f, 0.f, 0.f, 0.f};
  for (int k4 = 0; k4 < 128; ++k4) {
    float4 wv = Wf4[k4];
#pragma unroll
    for (int tt = 0; tt < 4; ++tt) {
      float4 xv = Xf4[(size_t)(t0 + tt) * 128 + k4];
      acc[tt] = fmaf(wv.x, xv.x, fmaf(wv.y, xv.y, fmaf(wv.z, xv.z, fmaf(wv.w, xv.w, acc[tt]))));
    }
  }
  float mc = mask_coarse[o & 255];
#pragma unroll
  for (int tt = 0; tt < 4; ++tt)
    eb[(size_t)(t0 + tt) * 2048 + o] = acc[tt] * mc;
}

// ---------------- K1: persistent scan. 256 blocks x 512 threads.
// 8 ch x (4x8 tiles of 64x32); 1 float4-group per thread. State in LDS;
// boundary exchanged via (payload,tag) atomics — no flags, no drain barrier.
__global__ __launch_bounds__(512, 2) void scan_kernel(
    const float* __restrict__ mask_fine, const float* __restrict__ W_deconv,
    const float* __restrict__ w1, const float* __restrict__ w2,
    const float* __restrict__ w_out, float* __restrict__ ws)
{
  __shared__ float zin[72 * 44];      // persistent tile + 4-halo (stride 44)
  __shared__ float rowbuf[64 * 19];   // per-row readout partials

  const int tid  = threadIdx.x;       // 0..511
  const int bid  = blockIdx.x;
  const int ch   = bid >> 5;
  const int tile = bid & 31;
  const int tI = tile >> 3, tJ = tile & 7;
  const int r0 = tI << 6, c0 = tJ << 5;
  const int row = tid >> 3;           // 0..63
  const int cg  = tid & 7;
  const int lc  = cg << 2;

  float* Zb = ws + SB_OFF;
  const float* eb = ws + E_OFF;
  float* yp = ws + YP_OFF;
  const int myoff = (ch * 32 + tile) << 11;   // record stride 2048

  // ---- per-thread fixed constants
  const int a16 = row & 15;
  const int b16 = lc & 15;
  const int i0  = (r0 + row) >> 4;
  const int jj  = (c0 + lc) >> 4;
  float4 wd[8];
#pragma unroll
  for (int c = 0; c < 8; ++c)
    wd[c] = *(const float4*)&W_deconv[(((c * 8 + ch) * 16) + a16) * 16 + b16];
  float4 mf = *(const float4*)&mask_fine[(size_t)(r0 + row) * 256 + c0 + lc];
  float4 wo[16];
#pragma unroll
  for (int oc = 0; oc < 16; ++oc)
    wo[oc] = *(const float4*)&w_out[(((oc * 8 + ch) * 32) + (row & 31)) * 32 + lc];
  float w1s[9], w2s[25];
#pragma unroll
  for (int k = 0; k < 9; ++k)
    w1s[k] = __uint_as_float(__builtin_amdgcn_readfirstlane(__float_as_uint(w1[ch * 9 + k])));
#pragma unroll
  for (int k = 0; k < 25; ++k)
    w2s[k] = __uint_as_float(__builtin_amdgcn_readfirstlane(__float_as_uint(w2[ch * 25 + k])));

  // ---- fixed halo-read assignments: 832 (payload,tag) words; <=2 per thread
  int rd_off[2] = {0, 0}, rd_dst[2] = {0, 0};
  {
    int n = 0;
    auto setup = [&](int u) {
      int di = 0, dj = 0, off = 0, dst = 0;
      if (u < 128) {            // top rows 0..3, cols 4..35  <- U.HB
        int r = u >> 5, c = u & 31;
        di = -1; dj = 0; off = 256 + 2 * u; dst = r * 44 + 4 + c;
      } else if (u < 256) {     // bottom rows 68..71         <- D.HT
        int v = u - 128;
        di = 1; dj = 0; off = 2 * v; dst = (68 + (v >> 5)) * 44 + 4 + (v & 31);
      } else if (u < 512) {     // left rows 4..67, cols 0..3 <- L.VR
        int v = u - 256;
        di = 0; dj = -1; off = 1024 + 2 * v; dst = (4 + (v >> 2)) * 44 + (v & 3);
      } else if (u < 768) {     // right rows 4..67, cols 36..39 <- R.VL
        int v = u - 512;
        di = 0; dj = 1; off = 512 + 2 * v; dst = (4 + (v >> 2)) * 44 + 36 + (v & 3);
      } else {                  // corners, 16 words each
        int v = u - 768; int corner = v >> 4, k = v & 15, r = k >> 2, c = k & 3;
        if (corner == 0)      { di = -1; dj = -1; off = 1632 + 2 * k; dst = r * 44 + c; }
        else if (corner == 1) { di = -1; dj = 1;  off = 1600 + 2 * k; dst = r * 44 + 36 + c; }
        else if (corner == 2) { di = 1;  dj = -1; off = 1568 + 2 * k; dst = (68 + r) * 44 + c; }
        else                  { di = 1;  dj = 1;  off = 1536 + 2 * k; dst = (68 + r) * 44 + 36 + c; }
      }
      int nI = (tI + di) & 3, nJ = (tJ + dj) & 7;
      rd_off[n] = ((ch * 32 + nI * 8 + nJ) << 11) + off;
      rd_dst[n] = dst;
      ++n;
    };
    setup(tid);
    if (tid < 320) setup(tid + 512);
  }
  const bool has2 = (tid < 320);

  // init persistent state (Z0 = 0, incl. halo)
  for (int k = tid; k < 72 * 44; k += 512) zin[k] = 0.f;
  __syncthreads();

  for (int t = 0; t < 128; ++t) {
    float* sb = Zb + (size_t)((t + 1) & 1) * 524288;   // tagged strips for Z_{t+1}

    // input-path e values (read-only, L2-resident)
    float ev[8];
#pragma unroll
    for (int c = 0; c < 8; ++c)
      ev[c] = eb[(size_t)t * 2048 + c * 256 + i0 * 16 + jj];

    // ---- compute Z_{t+1} for this thread's 4 px (reads zin = Z_t incl halo)
    float c1a[4] = {0, 0, 0, 0}, c2a[4] = {0, 0, 0, 0};
    {
      float w[12];
      auto load_row = [&](int zr) {
        float4 A  = *(const float4*)&zin[zr * 44 + lc];
        float4 B  = *(const float4*)&zin[zr * 44 + lc + 4];
        float4 Cq = *(const float4*)&zin[zr * 44 + lc + 8];
        w[0]=A.x; w[1]=A.y; w[2]=A.z; w[3]=A.w;
        w[4]=B.x; w[5]=B.y; w[6]=B.z; w[7]=B.w;
        w[8]=Cq.x; w[9]=Cq.y; w[10]=Cq.z; w[11]=Cq.w;
      };
      auto k2row = [&](int a) {
#pragma unroll
        for (int j = 0; j < 4; ++j)
#pragma unroll
          for (int b = 0; b < 5; ++b)
            c2a[j] = fmaf(w[j + 2 * b], w2s[a * 5 + b], c2a[j]);
      };
      auto k1row = [&](int a) {
#pragma unroll
        for (int j = 0; j < 4; ++j)
#pragma unroll
          for (int b = 0; b < 3; ++b)
            c1a[j] = fmaf(w[j + 3 + b], w1s[a * 3 + b], c1a[j]);
      };
      load_row(row + 0); k2row(0);
      load_row(row + 2); k2row(1);
      load_row(row + 3); k1row(0);
      load_row(row + 4); k1row(1); k2row(2);
      load_row(row + 5); k1row(2);
      load_row(row + 6); k2row(3);
      load_row(row + 8); k2row(4);
    }
    float zv[4];
    {
      const float* mfp = (const float*)&mf;
#pragma unroll
      for (int j = 0; j < 4; ++j) {
        float u = 0.f;
#pragma unroll
        for (int c = 0; c < 8; ++c)
          u = fmaf(ev[c], ((const float*)&wd[c])[j], u);
        float val = fmaf(0.9f, c1a[j], fmaf(0.1f, c2a[j], mfp[j] * u));
        zv[j] = fast_tanh(val);
      }
    }

    // ---- publish tagged boundary words NOW (before barrier A): max head start.
    // Safe: neighbor consumed the tag-(t-1) words in this parity before it
    // published tag t, which we already consumed to get here.
    if (t < 127) {
      float* myrec = sb + myoff;
      const float tagf = __uint_as_float((unsigned)(t + 1));
      if (row < 4) {
#pragma unroll
        for (int j = 0; j < 4; ++j)
          astore_f2(myrec + 2 * (row * 32 + lc + j), zv[j], tagf);           // HT
      }
      if (row >= 60) {
#pragma unroll
        for (int j = 0; j < 4; ++j)
          astore_f2(myrec + 256 + 2 * ((row - 60) * 32 + lc + j), zv[j], tagf); // HB
      }
      if (lc == 0) {
#pragma unroll
        for (int j = 0; j < 4; ++j)
          astore_f2(myrec + 512 + 2 * (row * 4 + j), zv[j], tagf);           // VL
      }
      if (lc == 28) {
#pragma unroll
        for (int j = 0; j < 4; ++j)
          astore_f2(myrec + 1024 + 2 * (row * 4 + j), zv[j], tagf);          // VR
      }
      if (row < 4 && lc == 0) {
#pragma unroll
        for (int j = 0; j < 4; ++j)
          astore_f2(myrec + 1536 + 2 * (row * 4 + j), zv[j], tagf);          // CTL
      }
      if (row < 4 && lc == 28) {
#pragma unroll
        for (int j = 0; j < 4; ++j)
          astore_f2(myrec + 1568 + 2 * (row * 4 + j), zv[j], tagf);          // CTR
      }
      if (row >= 60 && lc == 0) {
#pragma unroll
        for (int j = 0; j < 4; ++j)
          astore_f2(myrec + 1600 + 2 * ((row - 60) * 4 + j), zv[j], tagf);   // CBL
      }
      if (row >= 60 && lc == 28) {
#pragma unroll
        for (int j = 0; j < 4; ++j)
          astore_f2(myrec + 1632 + 2 * ((row - 60) * 4 + j), zv[j], tagf);   // CBR
      }
    }

    float racc[16];
#pragma unroll
    for (int oc = 0; oc < 16; ++oc) {
      const float* wop = (const float*)&wo[oc];
      racc[oc] = fmaf(zv[0], wop[0], fmaf(zv[1], wop[1], fmaf(zv[2], wop[2], zv[3] * wop[3])));
    }

    __syncthreads();  // A: all reads of Z_t from zin complete

    // ---- commit interior to LDS
    *(float4*)&zin[(4 + row) * 44 + 4 + lc] = make_float4(zv[0], zv[1], zv[2], zv[3]);

    // ---- readout reduction stage 1 (octet butterfly, off the LDS pipe)
#pragma unroll
    for (int m = 1; m <= 4; m <<= 1)
#pragma unroll
      for (int k = 0; k < 16; ++k)
        racc[k] += __shfl_xor(racc[k], m, 64);
    rowbuf[row * 19 + (cg << 1)]     = racc[cg << 1];
    rowbuf[row * 19 + (cg << 1) + 1] = racc[(cg << 1) + 1];

    // ---- halo: poll the tagged words directly (no flags, no drain)
    if (t < 127) {
      const unsigned tg = (unsigned)(t + 1);
      {
        const float* p = sb + rd_off[0];
        float2 v2; int spins = 0;
        do { v2 = aload_f2(p);
             if (__float_as_uint(v2.y) == tg) break;
             __builtin_amdgcn_s_sleep(1);
        } while (++spins < (1 << 17));   // fail loud (wrong), never hang
        zin[rd_dst[0]] = v2.x;
      }
      if (has2) {
        const float* p = sb + rd_off[1];
        float2 v2; int spins = 0;
        do { v2 = aload_f2(p);
             if (__float_as_uint(v2.y) == tg) break;
             __builtin_amdgcn_s_sleep(1);
        } while (++spins < (1 << 17));
        zin[rd_dst[1]] = v2.x;
      }
    }

    __syncthreads();  // B: zin (interior + halo) and rowbuf complete

    // ---- stage 2: 32 threads fold -> yp[t] (rowbuf reused only after next A)
    if (tid < 32) {
      int p = tid >> 4, oc = tid & 15;
      float s = 0.f;
#pragma unroll
      for (int r = 0; r < 32; ++r) s += rowbuf[(p * 32 + r) * 19 + oc];
      yp[(((size_t)ch * 64 + (2 * tI + p) * 8 + tJ) * 128 + t) * 16 + oc] = s;
    }
  }
}

// ---------------- K2: sum channel partials + bias -> out [128,16,8,8] flat
__global__ __launch_bounds__(256) void final_kernel(
    const float* __restrict__ b_out, const float* __restrict__ ws, float* __restrict__ out)
{
  int idx = blockIdx.x * 256 + threadIdx.x;  // 131072
  int t = idx >> 10;
  int rem = idx & 1023;
  int oc = rem >> 6;
  int IJ = rem & 63;
  const float* yp = ws + YP_OFF;
  float s = b_out[oc];
#pragma unroll
  for (int c = 0; c < 8; ++c)
    s += yp[(((size_t)c * 64 + IJ) * 128 + t) * 16 + oc];
  out[idx] = s;
}

extern "C" void kernel_launch(void* const* d_in, const int* in_sizes, int n_in,
                              void* d_out, int out_size, void* d_ws, size_t ws_size,
                              hipStream_t stream) {
  const float* X           = (const float*)d_in[0];
  const float* W_embed     = (const float*)d_in[1];
  const float* mask_coarse = (const float*)d_in[2];
  const float* mask_fine   = (const float*)d_in[3];
  const float* W_deconv    = (const float*)d_in[4];
  const float* w1          = (const float*)d_in[5];
  const float* w2          = (const float*)d_in[6];
  const float* w_out       = (const float*)d_in[7];
  const float* b_out       = (const float*)d_in[8];
  float* ws  = (float*)d_ws;
  float* out = (float*)d_out;

  prep_kernel<<<dim3(256), dim3(256), 0, stream>>>(X, W_embed, mask_coarse, ws);
  scan_kernel<<<dim3(256), dim3(512), 0, stream>>>(mask_fine, W_deconv, w1, w2, w_out, ws);
  final_kernel<<<dim3(512), dim3(256), 0, stream>>>(b_out, ws, out);
}

// Round 9
// 555.756 us; speedup vs baseline: 1.0721x; 1.0721x over previous
//
#include <hip/hip_runtime.h>
#include <math.h>

// ws layout (float offsets)
#define SB_OFF   0          // tagged strips [2][8][32][2048] = 1048576 floats
#define E_OFF    1048576    // e    [128][2048]      = 262144 floats
#define YP_OFF   1310720    // ypart[8][64][128][16] = 1048576 floats
// strip record (2048 floats/tile), all entries are (payload,tag) f2 pairs:
//   HT[4][32]@0  HB[4][32]@256  VL[64][4]@512  VR[64][4]@1024
//   CTL[4][4]@1536  CTR@1568  CBL@1600  CBR@1632   (offsets in floats)

__device__ __forceinline__ float fast_tanh(float x) {
  x = fminf(fmaxf(x, -15.f), 15.f);
  float ex = __expf(2.f * x);
  return __fdividef(ex - 1.f, ex + 1.f);
}

// octet (8-lane) sum via DPP — pure VALU, keeps the reduction off the LDS pipe.
// quad_perm(1,0,3,2)=0xB1 (xor1), quad_perm(2,3,0,1)=0x4E (xor2),
// row_half_mirror=0x141 (i<->7-i within each 8-lane half-row = cross-quad).
template <int CTRL>
__device__ __forceinline__ float dpp_add(float v) {
  int x = __builtin_amdgcn_update_dpp(0, __float_as_int(v), CTRL, 0xF, 0xF, true);
  return v + __int_as_float(x);
}

// Cross-XCD coherent data path: relaxed AGENT-scope atomics serviced at the
// coherent point (L2-bypass). 8B single-copy atomicity carries (payload,tag).
__device__ __forceinline__ float2 aload_f2(const float* p) {
  unsigned long long v = __hip_atomic_load((const unsigned long long*)p,
                                           __ATOMIC_RELAXED, __HIP_MEMORY_SCOPE_AGENT);
  float2 r;
  r.x = __uint_as_float((unsigned)v);
  r.y = __uint_as_float((unsigned)(v >> 32));
  return r;
}
__device__ __forceinline__ void astore_f2(float* p, float a, float b) {
  unsigned long long v =
      ((unsigned long long)__float_as_uint(b) << 32) | (unsigned long long)__float_as_uint(a);
  __hip_atomic_store((unsigned long long*)p, v, __ATOMIC_RELAXED, __HIP_MEMORY_SCOPE_AGENT);
}

// ---------------- K0: embed e = (X@W^T)*mask_coarse
__global__ __launch_bounds__(256) void prep_kernel(
    const float* __restrict__ X, const float* __restrict__ W_embed,
    const float* __restrict__ mask_coarse, float* __restrict__ ws)
{
  const int tid = threadIdx.x, bid = blockIdx.x;  // grid = 256
  float* eb = ws + E_OFF;
  const int o  = bid * 8 + (tid >> 5);     // 2048 output rows
  const int t0 = (tid & 31) * 4;           // 4 t's per thread
  const float4* Wf4 = (const float4*)W_embed + (size_t)o * 128;
  const float4* Xf4 = (const float4*)X;
  float acc[4] = {0.f, 0.f, 0.f, 0.f};
  for (int k4 = 0; k4 < 128; ++k4) {
    float4 wv = Wf4[k4];
#pragma unroll
    for (int tt = 0; tt < 4; ++tt) {
      float4 xv = Xf4[(size_t)(t0 + tt) * 128 + k4];
      acc[tt] = fmaf(wv.x, xv.x, fmaf(wv.y, xv.y, fmaf(wv.z, xv.z, fmaf(wv.w, xv.w, acc[tt]))));
    }
  }
  float mc = mask_coarse[o & 255];
#pragma unroll
  for (int tt = 0; tt < 4; ++tt)
    eb[(size_t)(t0 + tt) * 2048 + o] = acc[tt] * mc;
}

// ---------------- K1: persistent scan. 256 blocks x 512 threads.
// 8 ch x (4x8 tiles of 64x32); 1 float4-group per thread. State in LDS;
// boundary exchanged via (payload,tag) atomics — no flags, no drain barrier.
__global__ __launch_bounds__(512, 2) void scan_kernel(
    const float* __restrict__ mask_fine, const float* __restrict__ W_deconv,
    const float* __restrict__ w1, const float* __restrict__ w2,
    const float* __restrict__ w_out, float* __restrict__ ws)
{
  __shared__ float zin[72 * 44];      // persistent tile + 4-halo (stride 44)
  __shared__ float rowbuf[64 * 19];   // per-row readout partials

  const int tid  = threadIdx.x;       // 0..511
  const int bid  = blockIdx.x;
  const int ch   = bid >> 5;
  const int tile = bid & 31;
  const int tI = tile >> 3, tJ = tile & 7;
  const int r0 = tI << 6, c0 = tJ << 5;
  const int row = tid >> 3;           // 0..63
  const int cg  = tid & 7;
  const int lc  = cg << 2;

  float* Zb = ws + SB_OFF;
  const float* eb = ws + E_OFF;
  float* yp = ws + YP_OFF;
  const int myoff = (ch * 32 + tile) << 11;   // record stride 2048

  // ---- per-thread fixed constants
  const int a16 = row & 15;
  const int b16 = lc & 15;
  const int i0  = (r0 + row) >> 4;
  const int jj  = (c0 + lc) >> 4;
  float4 wd[8];
#pragma unroll
  for (int c = 0; c < 8; ++c)
    wd[c] = *(const float4*)&W_deconv[(((c * 8 + ch) * 16) + a16) * 16 + b16];
  float4 mf = *(const float4*)&mask_fine[(size_t)(r0 + row) * 256 + c0 + lc];
  float4 wo[16];
#pragma unroll
  for (int oc = 0; oc < 16; ++oc)
    wo[oc] = *(const float4*)&w_out[(((oc * 8 + ch) * 32) + (row & 31)) * 32 + lc];
  float w1s[9], w2s[25];
#pragma unroll
  for (int k = 0; k < 9; ++k)
    w1s[k] = __uint_as_float(__builtin_amdgcn_readfirstlane(__float_as_uint(w1[ch * 9 + k])));
#pragma unroll
  for (int k = 0; k < 25; ++k)
    w2s[k] = __uint_as_float(__builtin_amdgcn_readfirstlane(__float_as_uint(w2[ch * 25 + k])));

  // ---- fixed halo-read assignments: 832 (payload,tag) words; <=2 per thread
  int rd_off[2] = {0, 0}, rd_dst[2] = {0, 0};
  {
    int n = 0;
    auto setup = [&](int u) {
      int di = 0, dj = 0, off = 0, dst = 0;
      if (u < 128) {            // top rows 0..3, cols 4..35  <- U.HB
        int r = u >> 5, c = u & 31;
        di = -1; dj = 0; off = 256 + 2 * u; dst = r * 44 + 4 + c;
      } else if (u < 256) {     // bottom rows 68..71         <- D.HT
        int v = u - 128;
        di = 1; dj = 0; off = 2 * v; dst = (68 + (v >> 5)) * 44 + 4 + (v & 31);
      } else if (u < 512) {     // left rows 4..67, cols 0..3 <- L.VR
        int v = u - 256;
        di = 0; dj = -1; off = 1024 + 2 * v; dst = (4 + (v >> 2)) * 44 + (v & 3);
      } else if (u < 768) {     // right rows 4..67, cols 36..39 <- R.VL
        int v = u - 512;
        di = 0; dj = 1; off = 512 + 2 * v; dst = (4 + (v >> 2)) * 44 + 36 + (v & 3);
      } else {                  // corners, 16 words each
        int v = u - 768; int corner = v >> 4, k = v & 15, r = k >> 2, c = k & 3;
        if (corner == 0)      { di = -1; dj = -1; off = 1632 + 2 * k; dst = r * 44 + c; }
        else if (corner == 1) { di = -1; dj = 1;  off = 1600 + 2 * k; dst = r * 44 + 36 + c; }
        else if (corner == 2) { di = 1;  dj = -1; off = 1568 + 2 * k; dst = (68 + r) * 44 + c; }
        else                  { di = 1;  dj = 1;  off = 1536 + 2 * k; dst = (68 + r) * 44 + 36 + c; }
      }
      int nI = (tI + di) & 3, nJ = (tJ + dj) & 7;
      rd_off[n] = ((ch * 32 + nI * 8 + nJ) << 11) + off;
      rd_dst[n] = dst;
      ++n;
    };
    setup(tid);
    if (tid < 320) setup(tid + 512);
  }
  const bool has2 = (tid < 320);

  // init persistent state (Z0 = 0, incl. halo)
  for (int k = tid; k < 72 * 44; k += 512) zin[k] = 0.f;
  __syncthreads();

  for (int t = 0; t < 128; ++t) {
    float* sb = Zb + (size_t)((t + 1) & 1) * 524288;   // tagged strips for Z_{t+1}

    // input-path e values (read-only, L2-resident)
    float ev[8];
#pragma unroll
    for (int c = 0; c < 8; ++c)
      ev[c] = eb[(size_t)t * 2048 + c * 256 + i0 * 16 + jj];

    // ---- compute Z_{t+1} for this thread's 4 px (reads zin = Z_t incl halo)
    float c1a[4] = {0, 0, 0, 0}, c2a[4] = {0, 0, 0, 0};
    {
      float w[12];
      auto load_row = [&](int zr) {
        float4 A  = *(const float4*)&zin[zr * 44 + lc];
        float4 B  = *(const float4*)&zin[zr * 44 + lc + 4];
        float4 Cq = *(const float4*)&zin[zr * 44 + lc + 8];
        w[0]=A.x; w[1]=A.y; w[2]=A.z; w[3]=A.w;
        w[4]=B.x; w[5]=B.y; w[6]=B.z; w[7]=B.w;
        w[8]=Cq.x; w[9]=Cq.y; w[10]=Cq.z; w[11]=Cq.w;
      };
      auto k2row = [&](int a) {
#pragma unroll
        for (int j = 0; j < 4; ++j)
#pragma unroll
          for (int b = 0; b < 5; ++b)
            c2a[j] = fmaf(w[j + 2 * b], w2s[a * 5 + b], c2a[j]);
      };
      auto k1row = [&](int a) {
#pragma unroll
        for (int j = 0; j < 4; ++j)
#pragma unroll
          for (int b = 0; b < 3; ++b)
            c1a[j] = fmaf(w[j + 3 + b], w1s[a * 3 + b], c1a[j]);
      };
      load_row(row + 0); k2row(0);
      load_row(row + 2); k2row(1);
      load_row(row + 3); k1row(0);
      load_row(row + 4); k1row(1); k2row(2);
      load_row(row + 5); k1row(2);
      load_row(row + 6); k2row(3);
      load_row(row + 8); k2row(4);
    }
    float zv[4];
    {
      const float* mfp = (const float*)&mf;
#pragma unroll
      for (int j = 0; j < 4; ++j) {
        float u = 0.f;
#pragma unroll
        for (int c = 0; c < 8; ++c)
          u = fmaf(ev[c], ((const float*)&wd[c])[j], u);
        float val = fmaf(0.9f, c1a[j], fmaf(0.1f, c2a[j], mfp[j] * u));
        zv[j] = fast_tanh(val);
      }
    }

    // ---- publish tagged boundary words NOW (before barrier A): max head start.
    if (t < 127) {
      float* myrec = sb + myoff;
      const float tagf = __uint_as_float((unsigned)(t + 1));
      if (row < 4) {
#pragma unroll
        for (int j = 0; j < 4; ++j)
          astore_f2(myrec + 2 * (row * 32 + lc + j), zv[j], tagf);           // HT
      }
      if (row >= 60) {
#pragma unroll
        for (int j = 0; j < 4; ++j)
          astore_f2(myrec + 256 + 2 * ((row - 60) * 32 + lc + j), zv[j], tagf); // HB
      }
      if (lc == 0) {
#pragma unroll
        for (int j = 0; j < 4; ++j)
          astore_f2(myrec + 512 + 2 * (row * 4 + j), zv[j], tagf);           // VL
      }
      if (lc == 28) {
#pragma unroll
        for (int j = 0; j < 4; ++j)
          astore_f2(myrec + 1024 + 2 * (row * 4 + j), zv[j], tagf);          // VR
      }
      if (row < 4 && lc == 0) {
#pragma unroll
        for (int j = 0; j < 4; ++j)
          astore_f2(myrec + 1536 + 2 * (row * 4 + j), zv[j], tagf);          // CTL
      }
      if (row < 4 && lc == 28) {
#pragma unroll
        for (int j = 0; j < 4; ++j)
          astore_f2(myrec + 1568 + 2 * (row * 4 + j), zv[j], tagf);          // CTR
      }
      if (row >= 60 && lc == 0) {
#pragma unroll
        for (int j = 0; j < 4; ++j)
          astore_f2(myrec + 1600 + 2 * ((row - 60) * 4 + j), zv[j], tagf);   // CBL
      }
      if (row >= 60 && lc == 28) {
#pragma unroll
        for (int j = 0; j < 4; ++j)
          astore_f2(myrec + 1632 + 2 * ((row - 60) * 4 + j), zv[j], tagf);   // CBR
      }
    }

    float racc[16];
#pragma unroll
    for (int oc = 0; oc < 16; ++oc) {
      const float* wop = (const float*)&wo[oc];
      racc[oc] = fmaf(zv[0], wop[0], fmaf(zv[1], wop[1], fmaf(zv[2], wop[2], zv[3] * wop[3])));
    }

    __syncthreads();  // A: all reads of Z_t from zin complete

    // ---- commit interior to LDS
    *(float4*)&zin[(4 + row) * 44 + 4 + lc] = make_float4(zv[0], zv[1], zv[2], zv[3]);

    // ---- readout reduction stage 1: octet sum via DPP (VALU pipe, not LDS)
#pragma unroll
    for (int k = 0; k < 16; ++k) {
      racc[k] = dpp_add<0xB1>(racc[k]);    // + xor1 (quad_perm 1,0,3,2)
      racc[k] = dpp_add<0x4E>(racc[k]);    // + xor2 (quad_perm 2,3,0,1)
      racc[k] = dpp_add<0x141>(racc[k]);   // + cross-quad (row_half_mirror)
    }
    rowbuf[row * 19 + (cg << 1)]     = racc[cg << 1];
    rowbuf[row * 19 + (cg << 1) + 1] = racc[(cg << 1) + 1];

    // ---- halo: poll the tagged words directly (no flags, no drain)
    if (t < 127) {
      const unsigned tg = (unsigned)(t + 1);
      {
        const float* p = sb + rd_off[0];
        float2 v2; int spins = 0;
        do { v2 = aload_f2(p);
             if (__float_as_uint(v2.y) == tg) break;
             __builtin_amdgcn_s_sleep(1);
        } while (++spins < (1 << 17));   // fail loud (wrong), never hang
        zin[rd_dst[0]] = v2.x;
      }
      if (has2) {
        const float* p = sb + rd_off[1];
        float2 v2; int spins = 0;
        do { v2 = aload_f2(p);
             if (__float_as_uint(v2.y) == tg) break;
             __builtin_amdgcn_s_sleep(1);
        } while (++spins < (1 << 17));
        zin[rd_dst[1]] = v2.x;
      }
    }

    __syncthreads();  // B: zin (interior + halo) and rowbuf complete

    // ---- stage 2: 32 threads fold -> yp[t] (rowbuf reused only after next A)
    if (tid < 32) {
      int p = tid >> 4, oc = tid & 15;
      float s = 0.f;
#pragma unroll
      for (int r = 0; r < 32; ++r) s += rowbuf[(p * 32 + r) * 19 + oc];
      yp[(((size_t)ch * 64 + (2 * tI + p) * 8 + tJ) * 128 + t) * 16 + oc] = s;
    }
  }
}

// ---------------- K2: sum channel partials + bias -> out [128,16,8,8] flat
__global__ __launch_bounds__(256) void final_kernel(
    const float* __restrict__ b_out, const float* __restrict__ ws, float* __restrict__ out)
{
  int idx = blockIdx.x * 256 + threadIdx.x;  // 131072
  int t = idx >> 10;
  int rem = idx & 1023;
  int oc = rem >> 6;
  int IJ = rem & 63;
  const float* yp = ws + YP_OFF;
  float s = b_out[oc];
#pragma unroll
  for (int c = 0; c < 8; ++c)
    s += yp[(((size_t)c * 64 + IJ) * 128 + t) * 16 + oc];
  out[idx] = s;
}

extern "C" void kernel_launch(void* const* d_in, const int* in_sizes, int n_in,
                              void* d_out, int out_size, void* d_ws, size_t ws_size,
                              hipStream_t stream) {
  const float* X           = (const float*)d_in[0];
  const float* W_embed     = (const float*)d_in[1];
  const float* mask_coarse = (const float*)d_in[2];
  const float* mask_fine   = (const float*)d_in[3];
  const float* W_deconv    = (const float*)d_in[4];
  const float* w1          = (const float*)d_in[5];
  const float* w2          = (const float*)d_in[6];
  const float* w_out       = (const float*)d_in[7];
  const float* b_out       = (const float*)d_in[8];
  float* ws  = (float*)d_ws;
  float* out = (float*)d_out;

  prep_kernel<<<dim3(256), dim3(256), 0, stream>>>(X, W_embed, mask_coarse, ws);
  scan_kernel<<<dim3(256), dim3(512), 0, stream>>>(mask_fine, W_deconv, w1, w2, w_out, ws);
  final_kernel<<<dim3(512), dim3(256), 0, stream>>>(b_out, ws, out);
}